// Round 11
// baseline (215.507 us; speedup 1.0000x reference)
//
#include <hip/hip_runtime.h>

typedef __bf16 bf16x8 __attribute__((ext_vector_type(8)));
typedef float f32x4 __attribute__((ext_vector_type(4)));

__device__ __forceinline__ unsigned short f2bf(float f) {
  unsigned int u = __builtin_bit_cast(unsigned int, f);
  unsigned int r = (u + 0x7fffu + ((u >> 16) & 1u)) >> 16;
  return (unsigned short)r;
}

__device__ __forceinline__ float bf2f(unsigned short u) {
  unsigned int v = ((unsigned int)u) << 16;
  return __builtin_bit_cast(float, v);
}

__device__ __forceinline__ void load16_lds(const unsigned short* g, unsigned short* l) {
  __builtin_amdgcn_global_load_lds(
      (const __attribute__((address_space(1))) void*)g,
      (__attribute__((address_space(3))) void*)l, 16, 0, 0);
}

__device__ __forceinline__ void wait_vm0() {
  asm volatile("s_waitcnt vmcnt(0)" ::: "memory");
  __builtin_amdgcn_sched_barrier(0);
}
__device__ __forceinline__ void barrier_raw() {
  __builtin_amdgcn_sched_barrier(0);
  __builtin_amdgcn_s_barrier();
  __builtin_amdgcn_sched_barrier(0);
}

// ---------------- fused pre-pass: x cvt + W1/W2 transpose + W3t ----------------

__global__ __launch_bounds__(256) void prepass(
    const float* __restrict__ x, const float* __restrict__ W1,
    const float* __restrict__ W2, const float* __restrict__ W3,
    unsigned short* __restrict__ xbf, unsigned short* __restrict__ w1t,
    unsigned short* __restrict__ w2t, unsigned short* __restrict__ w3t) {
  __shared__ float tile[32][33];
  const int bid = blockIdx.x;
  const int t = threadIdx.x;
  if (bid < 2048) {
    for (int i = bid * 256 + t; i < 2097152; i += 2048 * 256) {
      float4 f = ((const float4*)x)[i];
      uint2 o;
      o.x = (unsigned)f2bf(f.x) | ((unsigned)f2bf(f.y) << 16);
      o.y = (unsigned)f2bf(f.z) | ((unsigned)f2bf(f.w) << 16);
      ((uint2*)xbf)[i] = o;
    }
  } else if (bid < 3072) {
    int ti = bid - 2048;
    int n0 = (ti & 31) * 32, k0 = (ti >> 5) * 32;
    int tx = t & 31, ty = t >> 5;
    #pragma unroll
    for (int r = 0; r < 32; r += 8)
      tile[ty + r][tx] = W1[(size_t)(k0 + ty + r) * 1024 + n0 + tx];
    __syncthreads();
    #pragma unroll
    for (int r = 0; r < 32; r += 8)
      w1t[(size_t)(n0 + ty + r) * 1024 + k0 + tx] = f2bf(tile[tx][ty + r]);
  } else if (bid < 5120) {
    int ti = bid - 3072;
    int n0 = (ti & 63) * 32, k0 = (ti >> 6) * 32;
    int tx = t & 31, ty = t >> 5;
    #pragma unroll
    for (int r = 0; r < 32; r += 8)
      tile[ty + r][tx] = W2[(size_t)(k0 + ty + r) * 2048 + n0 + tx];
    __syncthreads();
    #pragma unroll
    for (int r = 0; r < 32; r += 8)
      w2t[(size_t)(n0 + ty + r) * 1024 + k0 + tx] = f2bf(tile[tx][ty + r]);
  } else {
    int idx = (bid - 5120) * 256 + t;
    int n = idx >> 11, k = idx & 2047;
    w3t[idx] = f2bf((n < 50) ? W3[(size_t)k * 50 + n] : 0.f);
  }
}

// ---------------- GEMM1: 256x128 tile, 8 waves, 1 barrier/K-tile (R3 best) ----

__global__ __launch_bounds__(512, 2) void gemm1_8p(
    const unsigned short* __restrict__ A,
    const unsigned short* __restrict__ Bt,
    const float* __restrict__ bias,
    unsigned short* __restrict__ C) {
  constexpr int K = 1024, N = 1024, NT = 16;
  constexpr int AEL = 256 * 64;            // 16384 el
  constexpr int BEL = 128 * 64;            // 8192 el
  constexpr int BUF = AEL + BEL;           // 24576 el / 48 KB
  __shared__ __align__(16) unsigned short smem[2 * BUF];  // 96 KB
  const int t = threadIdx.x;
  const int m0 = blockIdx.x * 256;
  const int n0 = blockIdx.y * 128;
  const int lane = t & 63, wv = t >> 6;
  const int l16 = lane & 15, quad = lane >> 4;
  const int rb = (wv >> 1) * 64, cb = (wv & 1) * 64;

  const int srow = t >> 3;
  const int sg = ((t & 7) ^ (srow & 7)) * 8;  // pre-swizzled source granule
  const unsigned short* Ag0 = A + (size_t)(m0 + srow) * K + sg;
  const unsigned short* Bg0 = Bt + (size_t)(n0 + srow) * K + sg;
  const int ldsO = wv * 8 * 64;

  f32x4 acc[4][4] = {};

  #pragma unroll
  for (int r = 0; r < 4; ++r)
    load16_lds(Ag0 + (size_t)(r * 64) * K, &smem[r * 4096 + ldsO]);
  #pragma unroll
  for (int r = 0; r < 2; ++r)
    load16_lds(Bg0 + (size_t)(r * 64) * K, &smem[AEL + r * 4096 + ldsO]);

  for (int kt = 0; kt < NT; ++kt) {
    unsigned short* Ls = &smem[(kt & 1) * BUF];

    wait_vm0();      // drains tile kt's loads (issued a full tile ago)
    barrier_raw();   // publish buf[cur]; all prior reads of buf[next] retired

    if (kt + 1 < NT) {
      unsigned short* Ln = &smem[((kt + 1) & 1) * BUF];
      const unsigned short* An = Ag0 + (size_t)(kt + 1) * 64;
      const unsigned short* Bn = Bg0 + (size_t)(kt + 1) * 64;
      #pragma unroll
      for (int r = 0; r < 4; ++r)
        load16_lds(An + (size_t)(r * 64) * K, &Ln[r * 4096 + ldsO]);
      #pragma unroll
      for (int r = 0; r < 2; ++r)
        load16_lds(Bn + (size_t)(r * 64) * K, &Ln[AEL + r * 4096 + ldsO]);
    }

    #pragma unroll
    for (int half = 0; half < 2; ++half) {
      bf16x8 af[4], bfr[4];
      #pragma unroll
      for (int ni = 0; ni < 4; ++ni) {
        int row = cb + ni * 16 + l16;
        bfr[ni] = *(const bf16x8*)&Ls[AEL + row * 64 + ((half * 4 + quad) ^ (row & 7)) * 8];
      }
      #pragma unroll
      for (int mi = 0; mi < 4; ++mi) {
        int row = rb + mi * 16 + l16;
        af[mi] = *(const bf16x8*)&Ls[row * 64 + ((half * 4 + quad) ^ (row & 7)) * 8];
      }
      #pragma unroll
      for (int mi = 0; mi < 4; ++mi)
        #pragma unroll
        for (int ni = 0; ni < 4; ++ni)
          acc[mi][ni] = __builtin_amdgcn_mfma_f32_16x16x32_bf16(
              af[mi], bfr[ni], acc[mi][ni], 0, 0, 0);
    }
  }
  barrier_raw();

  unsigned short* Cs = smem;  // 256x128 bf16 = 64 KB
  float bv[4];
  #pragma unroll
  for (int ni = 0; ni < 4; ++ni) bv[ni] = bias[n0 + cb + ni * 16 + l16];
  #pragma unroll
  for (int mi = 0; mi < 4; ++mi)
    #pragma unroll
    for (int ni = 0; ni < 4; ++ni)
      #pragma unroll
      for (int r = 0; r < 4; ++r) {
        int row = rb + mi * 16 + quad * 4 + r;
        int col = cb + ni * 16 + l16;
        int pb = (col >> 3) ^ (row & 15);
        Cs[row * 128 + pb * 8 + (col & 7)] = f2bf(fmaxf(acc[mi][ni][r] + bv[ni], 0.f));
      }
  __syncthreads();
  #pragma unroll
  for (int j = 0; j < 8; ++j) {
    int idx = j * 512 + t;
    int row = idx >> 4, cg = idx & 15;
    int pb = cg ^ (row & 15);
    *(uint4*)&C[(size_t)(m0 + row) * N + n0 + cg * 8] =
        *(const uint4*)&Cs[row * 128 + pb * 8];
  }
}

// ---------------- GEMM2 (256x256) + fused GEMM3 partial, 1 barrier/K-tile ----
// R3 structure; partial layout [row][8][64] (z-minor) so the reducer reads
// all 8 partials of a row from one 1-KB line group.

__global__ __launch_bounds__(512, 2) void gemm2_8p(
    const unsigned short* __restrict__ A,    // h1 [8192,1024]
    const unsigned short* __restrict__ Bt,   // w2t [2048,1024]
    const float* __restrict__ bias,          // b2
    const unsigned short* __restrict__ W3t,  // [64,2048]
    unsigned short* __restrict__ part) {     // [8192][8][64]
  constexpr int K = 1024, NT = 16;
  constexpr int AEL = 256 * 64;
  constexpr int BUF = 2 * AEL;
  __shared__ __align__(16) unsigned short smem[2 * BUF];  // 128 KB
  const int t = threadIdx.x;
  const int m0 = blockIdx.x * 256;
  const int n0 = blockIdx.y * 256;
  const int lane = t & 63, wv = t >> 6;
  const int l16 = lane & 15, quad = lane >> 4;
  const int rb = (wv >> 2) * 128, cb = (wv & 3) * 64;

  const int srow = t >> 3;
  const int sg = ((t & 7) ^ (srow & 7)) * 8;
  const unsigned short* Ag0 = A + (size_t)(m0 + srow) * K + sg;
  const unsigned short* Bg0 = Bt + (size_t)(n0 + srow) * K + sg;
  const int ldsO = wv * 8 * 64;

  f32x4 acc[8][4] = {};

  #pragma unroll
  for (int r = 0; r < 4; ++r) {
    load16_lds(Ag0 + (size_t)(r * 64) * K, &smem[r * 4096 + ldsO]);
    load16_lds(Bg0 + (size_t)(r * 64) * K, &smem[AEL + r * 4096 + ldsO]);
  }

  for (int kt = 0; kt < NT; ++kt) {
    unsigned short* Ls = &smem[(kt & 1) * BUF];

    wait_vm0();
    barrier_raw();

    if (kt + 1 < NT) {
      unsigned short* Ln = &smem[((kt + 1) & 1) * BUF];
      const unsigned short* An = Ag0 + (size_t)(kt + 1) * 64;
      const unsigned short* Bn = Bg0 + (size_t)(kt + 1) * 64;
      #pragma unroll
      for (int r = 0; r < 4; ++r) {
        load16_lds(An + (size_t)(r * 64) * K, &Ln[r * 4096 + ldsO]);
        load16_lds(Bn + (size_t)(r * 64) * K, &Ln[AEL + r * 4096 + ldsO]);
      }
    }

    #pragma unroll
    for (int half = 0; half < 2; ++half) {
      bf16x8 bfr[4];
      #pragma unroll
      for (int ni = 0; ni < 4; ++ni) {
        int row = cb + ni * 16 + l16;
        bfr[ni] = *(const bf16x8*)&Ls[AEL + row * 64 + ((half * 4 + quad) ^ (row & 7)) * 8];
      }
      bf16x8 af[8];
      #pragma unroll
      for (int mi = 0; mi < 8; ++mi) {
        int row = rb + mi * 16 + l16;
        af[mi] = *(const bf16x8*)&Ls[row * 64 + ((half * 4 + quad) ^ (row & 7)) * 8];
      }
      #pragma unroll
      for (int mi = 0; mi < 8; ++mi)
        #pragma unroll
        for (int ni = 0; ni < 4; ++ni)
          acc[mi][ni] = __builtin_amdgcn_mfma_f32_16x16x32_bf16(
              af[mi], bfr[ni], acc[mi][ni], 0, 0, 0);
    }
  }
  barrier_raw();

  // epilogue 1: relu'd bf16 h2 tile into LDS (256x256, 32-granule XOR swizzle)
  unsigned short* Cs = smem;
  float bv[4];
  #pragma unroll
  for (int ni = 0; ni < 4; ++ni) bv[ni] = bias[n0 + cb + ni * 16 + l16];
  #pragma unroll
  for (int mi = 0; mi < 8; ++mi)
    #pragma unroll
    for (int ni = 0; ni < 4; ++ni)
      #pragma unroll
      for (int r = 0; r < 4; ++r) {
        int row = rb + mi * 16 + quad * 4 + r;
        int col = cb + ni * 16 + l16;
        int pb = (col >> 3) ^ (row & 31);
        Cs[row * 256 + pb * 8 + (col & 7)] = f2bf(fmaxf(acc[mi][ni][r] + bv[ni], 0.f));
      }
  __syncthreads();

  // epilogue 2: mini-GEMM 256x64 over K2=256
  bf16x8 bq[8][4];
  #pragma unroll
  for (int ks = 0; ks < 8; ++ks)
    #pragma unroll
    for (int nt = 0; nt < 4; ++nt)
      bq[ks][nt] = *(const bf16x8*)&W3t[(size_t)(nt * 16 + l16) * 2048 +
                                        n0 + ks * 32 + quad * 8];
  f32x4 acc2[2][4] = {};
  #pragma unroll
  for (int ks = 0; ks < 8; ++ks) {
    bf16x8 af2[2];
    #pragma unroll
    for (int mt = 0; mt < 2; ++mt) {
      int row = wv * 32 + mt * 16 + l16;
      int pb = (ks * 4 + quad) ^ (row & 31);
      af2[mt] = *(const bf16x8*)&Cs[row * 256 + pb * 8];
    }
    #pragma unroll
    for (int mt = 0; mt < 2; ++mt)
      #pragma unroll
      for (int nt = 0; nt < 4; ++nt)
        acc2[mt][nt] = __builtin_amdgcn_mfma_f32_16x16x32_bf16(
            af2[mt], bq[ks][nt], acc2[mt][nt], 0, 0, 0);
  }

  // epilogue 3: bf16 partial stores, z-minor layout [row][8][64]
  const int zi = blockIdx.y;
  #pragma unroll
  for (int mt = 0; mt < 2; ++mt)
    #pragma unroll
    for (int nt = 0; nt < 4; ++nt) {
      int col = nt * 16 + l16;
      #pragma unroll
      for (int r = 0; r < 4; ++r) {
        int row = m0 + wv * 32 + mt * 16 + quad * 4 + r;
        part[((size_t)row * 8 + zi) * 64 + col] = f2bf(acc2[mt][nt][r]);
      }
    }
}

// ---------------- geometry: atomic-free, z-minor partial reduction ----------

__global__ __launch_bounds__(256) void geom_reduce(
    const unsigned short* __restrict__ part,  // [8192][8][64]
    const float* __restrict__ b3,
    float* __restrict__ outp) {
  __shared__ float s_out3[16 * 64];        // 4 KB
  __shared__ float unfold[16][16][50];     // 51.2 KB, per-(item,patch) slab
  const int t = threadIdx.x;
  const int bbase = blockIdx.x * 16;

  // phase A: 8-way partial reduce (all 8 partials of a row within 1 KB)
  for (int i = t; i < 1024; i += 256) {
    int m = i >> 6, n = i & 63;
    const unsigned short* p = part + ((size_t)(bbase + m) * 8) * 64 + n;
    float v = 0.f;
    #pragma unroll
    for (int z = 0; z < 8; ++z) v += bf2f(p[z * 64]);
    s_out3[i] = v + ((n < 50) ? b3[n] : 0.f);
  }
  __syncthreads();

  // phase B: per (item, patch): homography + 25 warped points -> private slab
  {
    const int bl = t >> 4;
    const int p = t & 15;
    const int pi = p >> 2, pj = p & 3;
    const float* o = &s_out3[bl * 64];

    float u00 = 128.f * pi       + o[pi * 5 + pj];
    float v00 = 128.f * pj       + o[25 + pi * 5 + pj];
    float u01 = 128.f * pi       + o[pi * 5 + pj + 1];
    float v01 = 128.f * (pj + 1) + o[25 + pi * 5 + pj + 1];
    float u10 = 128.f * (pi + 1) + o[(pi + 1) * 5 + pj];
    float v10 = 128.f * pj       + o[25 + (pi + 1) * 5 + pj];
    float u11 = 128.f * (pi + 1) + o[(pi + 1) * 5 + pj + 1];
    float v11 = 128.f * (pj + 1) + o[25 + (pi + 1) * 5 + pj + 1];

    float sx = u00 - u10 + u11 - u01;
    float sy = v00 - v10 + v11 - v01;
    float dx1 = u10 - u11, dx2 = u01 - u11;
    float dy1 = v10 - v11, dy2 = v01 - v11;
    float rden = 1.f / (dx1 * dy2 - dx2 * dy1);
    float g = (sx * dy2 - dx2 * sy) * rden;
    float h = (dx1 * sy - sx * dy1) * rden;
    float a = u10 - u00 + g * u10;
    float b = u01 - u00 + h * u01;
    float c = u00;
    float d = v10 - v00 + g * v10;
    float e = v01 - v00 + h * v01;
    float f = v00;

    #pragma unroll
    for (int ai = 0; ai < 5; ++ai) {
      #pragma unroll
      for (int bi = 0; bi < 5; ++bi) {
        float s = 0.25f * ai, tt = 0.25f * bi;
        float rw = 1.f / (g * s + h * tt + 1.f);
        unfold[bl][p][ai * 5 + bi]      = (a * s + b * tt + c) * rw;
        unfold[bl][p][25 + ai * 5 + bi] = (d * s + e * tt + f) * rw;
      }
    }
  }
  __syncthreads();

  // phase C: gather <=4 covering patches per output cell (no atomics)
  for (int i = t; i < 16 * 578; i += 256) {
    int blb = i / 578;
    int rem = i - blb * 578;
    int ch = rem / 289;
    int ij = rem - ch * 289;
    int gi = ij / 17, gj = ij - gi * 17;

    int pi0 = (gi == 16) ? 3 : (gi >> 2);
    int ai0 = gi - 4 * pi0;
    int ci = (((gi & 3) == 0) && gi != 0 && gi != 16) ? 2 : 1;
    int pj0 = (gj == 16) ? 3 : (gj >> 2);
    int bj0 = gj - 4 * pj0;
    int cj = (((gj & 3) == 0) && gj != 0 && gj != 16) ? 2 : 1;

    float val = 0.f;
    #pragma unroll
    for (int ii = 0; ii < 2; ++ii) {
      if (ii < ci) {
        int pi = pi0 - ii, ai = ii ? 4 : ai0;
        #pragma unroll
        for (int jj = 0; jj < 2; ++jj) {
          if (jj < cj) {
            int pj = pj0 - jj, bi = jj ? 4 : bj0;
            val += unfold[blb][pi * 4 + pj][ch * 25 + ai * 5 + bi];
          }
        }
      }
    }

    if (((gi & 3) == 0) && ((gj & 3) == 0)) val *= 0.5f;
    if ((gi == 0 || gi == 16) && (gj == 0 || gj == 16)) val *= 2.f;
    val -= (ch == 0) ? 32.f * gi : 32.f * gj;
    outp[(size_t)(bbase + blb) * 578 + rem] = val;
  }
}

// ---------------- launch ----------------

extern "C" void kernel_launch(void* const* d_in, const int* in_sizes, int n_in,
                              void* d_out, int out_size, void* d_ws, size_t ws_size,
                              hipStream_t stream) {
  const float* x  = (const float*)d_in[0];
  const float* W1 = (const float*)d_in[1];
  const float* b1 = (const float*)d_in[2];
  const float* W2 = (const float*)d_in[3];
  const float* b2 = (const float*)d_in[4];
  const float* W3 = (const float*)d_in[5];
  const float* b3 = (const float*)d_in[6];
  float* outp = (float*)d_out;

  // workspace (~54.5 MB), lifetime aliasing:
  //   [0,8.39M)     part[8192][8][64] bf16 — aliases xbf[0,16M),
  //                 xbf dead before gemm2_8p writes part
  //   [34M,38M)     w2t
  //   [38M,38.25M)  w3t
  //   [38.5M,54.5M) h1
  char* ws = (char*)d_ws;
  unsigned short* xbf = (unsigned short*)ws;
  unsigned short* w1t = (unsigned short*)(ws + (size_t)16 * 1024 * 1024);
  unsigned short* part = (unsigned short*)ws;
  unsigned short* w2t = (unsigned short*)(ws + (size_t)34 * 1024 * 1024);
  unsigned short* w3t = (unsigned short*)(ws + (size_t)38 * 1024 * 1024);
  unsigned short* h1  = (unsigned short*)(ws + (size_t)38 * 1024 * 1024 + 512 * 1024);

  prepass<<<5632, 256, 0, stream>>>(x, W1, W2, W3, xbf, w1t, w2t, w3t);

  gemm1_8p<<<dim3(32, 8), 512, 0, stream>>>(xbf, w1t, b1, h1);
  gemm2_8p<<<dim3(64, 8), 512, 0, stream>>>(h1, w2t, b2, w3t, part);
  geom_reduce<<<512, 256, 0, stream>>>(part, b3, outp);
}

// Round 12
// 176.805 us; speedup vs baseline: 1.2189x; 1.2189x over previous
//
#include <hip/hip_runtime.h>

typedef __bf16 bf16x8 __attribute__((ext_vector_type(8)));
typedef float f32x4 __attribute__((ext_vector_type(4)));

__device__ __forceinline__ unsigned short f2bf(float f) {
  unsigned int u = __builtin_bit_cast(unsigned int, f);
  unsigned int r = (u + 0x7fffu + ((u >> 16) & 1u)) >> 16;
  return (unsigned short)r;
}

__device__ __forceinline__ float bf2f(unsigned short u) {
  unsigned int v = ((unsigned int)u) << 16;
  return __builtin_bit_cast(float, v);
}

__device__ __forceinline__ void load16_lds(const unsigned short* g, unsigned short* l) {
  __builtin_amdgcn_global_load_lds(
      (const __attribute__((address_space(1))) void*)g,
      (__attribute__((address_space(3))) void*)l, 16, 0, 0);
}

__device__ __forceinline__ void wait_vm0() {
  asm volatile("s_waitcnt vmcnt(0)" ::: "memory");
  __builtin_amdgcn_sched_barrier(0);
}
__device__ __forceinline__ void barrier_raw() {
  __builtin_amdgcn_sched_barrier(0);
  __builtin_amdgcn_s_barrier();
  __builtin_amdgcn_sched_barrier(0);
}

// ---------------- fused pre-pass: x cvt + W1/W2 transpose + W3t ----------------

__global__ __launch_bounds__(256) void prepass(
    const float* __restrict__ x, const float* __restrict__ W1,
    const float* __restrict__ W2, const float* __restrict__ W3,
    unsigned short* __restrict__ xbf, unsigned short* __restrict__ w1t,
    unsigned short* __restrict__ w2t, unsigned short* __restrict__ w3t) {
  __shared__ float tile[32][33];
  const int bid = blockIdx.x;
  const int t = threadIdx.x;
  if (bid < 2048) {
    for (int i = bid * 256 + t; i < 2097152; i += 2048 * 256) {
      float4 f = ((const float4*)x)[i];
      uint2 o;
      o.x = (unsigned)f2bf(f.x) | ((unsigned)f2bf(f.y) << 16);
      o.y = (unsigned)f2bf(f.z) | ((unsigned)f2bf(f.w) << 16);
      ((uint2*)xbf)[i] = o;
    }
  } else if (bid < 3072) {
    int ti = bid - 2048;
    int n0 = (ti & 31) * 32, k0 = (ti >> 5) * 32;
    int tx = t & 31, ty = t >> 5;
    #pragma unroll
    for (int r = 0; r < 32; r += 8)
      tile[ty + r][tx] = W1[(size_t)(k0 + ty + r) * 1024 + n0 + tx];
    __syncthreads();
    #pragma unroll
    for (int r = 0; r < 32; r += 8)
      w1t[(size_t)(n0 + ty + r) * 1024 + k0 + tx] = f2bf(tile[tx][ty + r]);
  } else if (bid < 5120) {
    int ti = bid - 3072;
    int n0 = (ti & 63) * 32, k0 = (ti >> 6) * 32;
    int tx = t & 31, ty = t >> 5;
    #pragma unroll
    for (int r = 0; r < 32; r += 8)
      tile[ty + r][tx] = W2[(size_t)(k0 + ty + r) * 2048 + n0 + tx];
    __syncthreads();
    #pragma unroll
    for (int r = 0; r < 32; r += 8)
      w2t[(size_t)(n0 + ty + r) * 1024 + k0 + tx] = f2bf(tile[tx][ty + r]);
  } else {
    int idx = (bid - 5120) * 256 + t;
    int n = idx >> 11, k = idx & 2047;
    w3t[idx] = f2bf((n < 50) ? W3[(size_t)k * 50 + n] : 0.f);
  }
}

// ---------------- GEMM1: 256x128 tile, 8 waves, 1 barrier/K-tile (R3 best) ----

__global__ __launch_bounds__(512, 2) void gemm1_8p(
    const unsigned short* __restrict__ A,
    const unsigned short* __restrict__ Bt,
    const float* __restrict__ bias,
    unsigned short* __restrict__ C) {
  constexpr int K = 1024, N = 1024, NT = 16;
  constexpr int AEL = 256 * 64;            // 16384 el
  constexpr int BEL = 128 * 64;            // 8192 el
  constexpr int BUF = AEL + BEL;           // 24576 el / 48 KB
  __shared__ __align__(16) unsigned short smem[2 * BUF];  // 96 KB
  const int t = threadIdx.x;
  const int m0 = blockIdx.x * 256;
  const int n0 = blockIdx.y * 128;
  const int lane = t & 63, wv = t >> 6;
  const int l16 = lane & 15, quad = lane >> 4;
  const int rb = (wv >> 1) * 64, cb = (wv & 1) * 64;

  const int srow = t >> 3;
  const int sg = ((t & 7) ^ (srow & 7)) * 8;  // pre-swizzled source granule
  const unsigned short* Ag0 = A + (size_t)(m0 + srow) * K + sg;
  const unsigned short* Bg0 = Bt + (size_t)(n0 + srow) * K + sg;
  const int ldsO = wv * 8 * 64;

  f32x4 acc[4][4] = {};

  #pragma unroll
  for (int r = 0; r < 4; ++r)
    load16_lds(Ag0 + (size_t)(r * 64) * K, &smem[r * 4096 + ldsO]);
  #pragma unroll
  for (int r = 0; r < 2; ++r)
    load16_lds(Bg0 + (size_t)(r * 64) * K, &smem[AEL + r * 4096 + ldsO]);

  for (int kt = 0; kt < NT; ++kt) {
    unsigned short* Ls = &smem[(kt & 1) * BUF];

    wait_vm0();      // drains tile kt's loads (issued a full tile ago)
    barrier_raw();   // publish buf[cur]; all prior reads of buf[next] retired

    if (kt + 1 < NT) {
      unsigned short* Ln = &smem[((kt + 1) & 1) * BUF];
      const unsigned short* An = Ag0 + (size_t)(kt + 1) * 64;
      const unsigned short* Bn = Bg0 + (size_t)(kt + 1) * 64;
      #pragma unroll
      for (int r = 0; r < 4; ++r)
        load16_lds(An + (size_t)(r * 64) * K, &Ln[r * 4096 + ldsO]);
      #pragma unroll
      for (int r = 0; r < 2; ++r)
        load16_lds(Bn + (size_t)(r * 64) * K, &Ln[AEL + r * 4096 + ldsO]);
    }

    #pragma unroll
    for (int half = 0; half < 2; ++half) {
      bf16x8 af[4], bfr[4];
      #pragma unroll
      for (int ni = 0; ni < 4; ++ni) {
        int row = cb + ni * 16 + l16;
        bfr[ni] = *(const bf16x8*)&Ls[AEL + row * 64 + ((half * 4 + quad) ^ (row & 7)) * 8];
      }
      #pragma unroll
      for (int mi = 0; mi < 4; ++mi) {
        int row = rb + mi * 16 + l16;
        af[mi] = *(const bf16x8*)&Ls[row * 64 + ((half * 4 + quad) ^ (row & 7)) * 8];
      }
      #pragma unroll
      for (int mi = 0; mi < 4; ++mi)
        #pragma unroll
        for (int ni = 0; ni < 4; ++ni)
          acc[mi][ni] = __builtin_amdgcn_mfma_f32_16x16x32_bf16(
              af[mi], bfr[ni], acc[mi][ni], 0, 0, 0);
    }
  }
  barrier_raw();

  unsigned short* Cs = smem;  // 256x128 bf16 = 64 KB
  float bv[4];
  #pragma unroll
  for (int ni = 0; ni < 4; ++ni) bv[ni] = bias[n0 + cb + ni * 16 + l16];
  #pragma unroll
  for (int mi = 0; mi < 4; ++mi)
    #pragma unroll
    for (int ni = 0; ni < 4; ++ni)
      #pragma unroll
      for (int r = 0; r < 4; ++r) {
        int row = rb + mi * 16 + quad * 4 + r;
        int col = cb + ni * 16 + l16;
        int pb = (col >> 3) ^ (row & 15);
        Cs[row * 128 + pb * 8 + (col & 7)] = f2bf(fmaxf(acc[mi][ni][r] + bv[ni], 0.f));
      }
  __syncthreads();
  #pragma unroll
  for (int j = 0; j < 8; ++j) {
    int idx = j * 512 + t;
    int row = idx >> 4, cg = idx & 15;
    int pb = cg ^ (row & 15);
    *(uint4*)&C[(size_t)(m0 + row) * N + n0 + cg * 8] =
        *(const uint4*)&Cs[row * 128 + pb * 8];
  }
}

// ---------------- GEMM2 (256x256) + fused GEMM3 partial, 1 barrier/K-tile ----
// R3 structure; partial layout [row][8][64] (z-minor) so the reducer reads
// all 8 partials of a row from one 1-KB line group.

__global__ __launch_bounds__(512, 2) void gemm2_8p(
    const unsigned short* __restrict__ A,    // h1 [8192,1024]
    const unsigned short* __restrict__ Bt,   // w2t [2048,1024]
    const float* __restrict__ bias,          // b2
    const unsigned short* __restrict__ W3t,  // [64,2048]
    unsigned short* __restrict__ part) {     // [8192][8][64]
  constexpr int K = 1024, NT = 16;
  constexpr int AEL = 256 * 64;
  constexpr int BUF = 2 * AEL;
  __shared__ __align__(16) unsigned short smem[2 * BUF];  // 128 KB
  const int t = threadIdx.x;
  const int m0 = blockIdx.x * 256;
  const int n0 = blockIdx.y * 256;
  const int lane = t & 63, wv = t >> 6;
  const int l16 = lane & 15, quad = lane >> 4;
  const int rb = (wv >> 2) * 128, cb = (wv & 3) * 64;

  const int srow = t >> 3;
  const int sg = ((t & 7) ^ (srow & 7)) * 8;
  const unsigned short* Ag0 = A + (size_t)(m0 + srow) * K + sg;
  const unsigned short* Bg0 = Bt + (size_t)(n0 + srow) * K + sg;
  const int ldsO = wv * 8 * 64;

  f32x4 acc[8][4] = {};

  #pragma unroll
  for (int r = 0; r < 4; ++r) {
    load16_lds(Ag0 + (size_t)(r * 64) * K, &smem[r * 4096 + ldsO]);
    load16_lds(Bg0 + (size_t)(r * 64) * K, &smem[AEL + r * 4096 + ldsO]);
  }

  for (int kt = 0; kt < NT; ++kt) {
    unsigned short* Ls = &smem[(kt & 1) * BUF];

    wait_vm0();
    barrier_raw();

    if (kt + 1 < NT) {
      unsigned short* Ln = &smem[((kt + 1) & 1) * BUF];
      const unsigned short* An = Ag0 + (size_t)(kt + 1) * 64;
      const unsigned short* Bn = Bg0 + (size_t)(kt + 1) * 64;
      #pragma unroll
      for (int r = 0; r < 4; ++r) {
        load16_lds(An + (size_t)(r * 64) * K, &Ln[r * 4096 + ldsO]);
        load16_lds(Bn + (size_t)(r * 64) * K, &Ln[AEL + r * 4096 + ldsO]);
      }
    }

    #pragma unroll
    for (int half = 0; half < 2; ++half) {
      bf16x8 bfr[4];
      #pragma unroll
      for (int ni = 0; ni < 4; ++ni) {
        int row = cb + ni * 16 + l16;
        bfr[ni] = *(const bf16x8*)&Ls[AEL + row * 64 + ((half * 4 + quad) ^ (row & 7)) * 8];
      }
      bf16x8 af[8];
      #pragma unroll
      for (int mi = 0; mi < 8; ++mi) {
        int row = rb + mi * 16 + l16;
        af[mi] = *(const bf16x8*)&Ls[row * 64 + ((half * 4 + quad) ^ (row & 7)) * 8];
      }
      #pragma unroll
      for (int mi = 0; mi < 8; ++mi)
        #pragma unroll
        for (int ni = 0; ni < 4; ++ni)
          acc[mi][ni] = __builtin_amdgcn_mfma_f32_16x16x32_bf16(
              af[mi], bfr[ni], acc[mi][ni], 0, 0, 0);
    }
  }
  barrier_raw();

  // epilogue 1: relu'd bf16 h2 tile into LDS (256x256, 32-granule XOR swizzle)
  unsigned short* Cs = smem;
  float bv[4];
  #pragma unroll
  for (int ni = 0; ni < 4; ++ni) bv[ni] = bias[n0 + cb + ni * 16 + l16];
  #pragma unroll
  for (int mi = 0; mi < 8; ++mi)
    #pragma unroll
    for (int ni = 0; ni < 4; ++ni)
      #pragma unroll
      for (int r = 0; r < 4; ++r) {
        int row = rb + mi * 16 + quad * 4 + r;
        int col = cb + ni * 16 + l16;
        int pb = (col >> 3) ^ (row & 31);
        Cs[row * 256 + pb * 8 + (col & 7)] = f2bf(fmaxf(acc[mi][ni][r] + bv[ni], 0.f));
      }
  __syncthreads();

  // epilogue 2: mini-GEMM 256x64 over K2=256
  bf16x8 bq[8][4];
  #pragma unroll
  for (int ks = 0; ks < 8; ++ks)
    #pragma unroll
    for (int nt = 0; nt < 4; ++nt)
      bq[ks][nt] = *(const bf16x8*)&W3t[(size_t)(nt * 16 + l16) * 2048 +
                                        n0 + ks * 32 + quad * 8];
  f32x4 acc2[2][4] = {};
  #pragma unroll
  for (int ks = 0; ks < 8; ++ks) {
    bf16x8 af2[2];
    #pragma unroll
    for (int mt = 0; mt < 2; ++mt) {
      int row = wv * 32 + mt * 16 + l16;
      int pb = (ks * 4 + quad) ^ (row & 31);
      af2[mt] = *(const bf16x8*)&Cs[row * 256 + pb * 8];
    }
    #pragma unroll
    for (int mt = 0; mt < 2; ++mt)
      #pragma unroll
      for (int nt = 0; nt < 4; ++nt)
        acc2[mt][nt] = __builtin_amdgcn_mfma_f32_16x16x32_bf16(
            af2[mt], bq[ks][nt], acc2[mt][nt], 0, 0, 0);
  }

  // epilogue 3: bf16 partial stores, z-minor layout [row][8][64]
  const int zi = blockIdx.y;
  #pragma unroll
  for (int mt = 0; mt < 2; ++mt)
    #pragma unroll
    for (int nt = 0; nt < 4; ++nt) {
      int col = nt * 16 + l16;
      #pragma unroll
      for (int r = 0; r < 4; ++r) {
        int row = m0 + wv * 32 + mt * 16 + quad * 4 + r;
        part[((size_t)row * 8 + zi) * 64 + col] = f2bf(acc2[mt][nt][r]);
      }
    }
}

// ---------------- geometry: atomic-free, z-minor partial reduction ----------

__global__ __launch_bounds__(256) void geom_reduce(
    const unsigned short* __restrict__ part,  // [8192][8][64]
    const float* __restrict__ b3,
    float* __restrict__ outp) {
  __shared__ float s_out3[16 * 64];        // 4 KB
  __shared__ float unfold[16][16][50];     // 51.2 KB, per-(item,patch) slab
  const int t = threadIdx.x;
  const int bbase = blockIdx.x * 16;

  // phase A: 8-way partial reduce (all 8 partials of a row within 1 KB)
  for (int i = t; i < 1024; i += 256) {
    int m = i >> 6, n = i & 63;
    const unsigned short* p = part + ((size_t)(bbase + m) * 8) * 64 + n;
    float v = 0.f;
    #pragma unroll
    for (int z = 0; z < 8; ++z) v += bf2f(p[z * 64]);
    s_out3[i] = v + ((n < 50) ? b3[n] : 0.f);
  }
  __syncthreads();

  // phase B: per (item, patch): homography + 25 warped points -> private slab
  {
    const int bl = t >> 4;
    const int p = t & 15;
    const int pi = p >> 2, pj = p & 3;
    const float* o = &s_out3[bl * 64];

    float u00 = 128.f * pi       + o[pi * 5 + pj];
    float v00 = 128.f * pj       + o[25 + pi * 5 + pj];
    float u01 = 128.f * pi       + o[pi * 5 + pj + 1];
    float v01 = 128.f * (pj + 1) + o[25 + pi * 5 + pj + 1];
    float u10 = 128.f * (pi + 1) + o[(pi + 1) * 5 + pj];
    float v10 = 128.f * pj       + o[25 + (pi + 1) * 5 + pj];
    float u11 = 128.f * (pi + 1) + o[(pi + 1) * 5 + pj + 1];
    float v11 = 128.f * (pj + 1) + o[25 + (pi + 1) * 5 + pj + 1];

    float sx = u00 - u10 + u11 - u01;
    float sy = v00 - v10 + v11 - v01;
    float dx1 = u10 - u11, dx2 = u01 - u11;
    float dy1 = v10 - v11, dy2 = v01 - v11;
    float rden = 1.f / (dx1 * dy2 - dx2 * dy1);
    float g = (sx * dy2 - dx2 * sy) * rden;
    float h = (dx1 * sy - sx * dy1) * rden;
    float a = u10 - u00 + g * u10;
    float b = u01 - u00 + h * u01;
    float c = u00;
    float d = v10 - v00 + g * v10;
    float e = v01 - v00 + h * v01;
    float f = v00;

    #pragma unroll
    for (int ai = 0; ai < 5; ++ai) {
      #pragma unroll
      for (int bi = 0; bi < 5; ++bi) {
        float s = 0.25f * ai, tt = 0.25f * bi;
        float rw = 1.f / (g * s + h * tt + 1.f);
        unfold[bl][p][ai * 5 + bi]      = (a * s + b * tt + c) * rw;
        unfold[bl][p][25 + ai * 5 + bi] = (d * s + e * tt + f) * rw;
      }
    }
  }
  __syncthreads();

  // phase C: gather <=4 covering patches per output cell (no atomics)
  for (int i = t; i < 16 * 578; i += 256) {
    int blb = i / 578;
    int rem = i - blb * 578;
    int ch = rem / 289;
    int ij = rem - ch * 289;
    int gi = ij / 17, gj = ij - gi * 17;

    int pi0 = (gi == 16) ? 3 : (gi >> 2);
    int ai0 = gi - 4 * pi0;
    int ci = (((gi & 3) == 0) && gi != 0 && gi != 16) ? 2 : 1;
    int pj0 = (gj == 16) ? 3 : (gj >> 2);
    int bj0 = gj - 4 * pj0;
    int cj = (((gj & 3) == 0) && gj != 0 && gj != 16) ? 2 : 1;

    float val = 0.f;
    #pragma unroll
    for (int ii = 0; ii < 2; ++ii) {
      if (ii < ci) {
        int pi = pi0 - ii, ai = ii ? 4 : ai0;
        #pragma unroll
        for (int jj = 0; jj < 2; ++jj) {
          if (jj < cj) {
            int pj = pj0 - jj, bi = jj ? 4 : bj0;
            val += unfold[blb][pi * 4 + pj][ch * 25 + ai * 5 + bi];
          }
        }
      }
    }

    if (((gi & 3) == 0) && ((gj & 3) == 0)) val *= 0.5f;
    if ((gi == 0 || gi == 16) && (gj == 0 || gj == 16)) val *= 2.f;
    val -= (ch == 0) ? 32.f * gi : 32.f * gj;
    outp[(size_t)(bbase + blb) * 578 + rem] = val;
  }
}

// ---------------- launch ----------------

extern "C" void kernel_launch(void* const* d_in, const int* in_sizes, int n_in,
                              void* d_out, int out_size, void* d_ws, size_t ws_size,
                              hipStream_t stream) {
  const float* x  = (const float*)d_in[0];
  const float* W1 = (const float*)d_in[1];
  const float* b1 = (const float*)d_in[2];
  const float* W2 = (const float*)d_in[3];
  const float* b2 = (const float*)d_in[4];
  const float* W3 = (const float*)d_in[5];
  const float* b3 = (const float*)d_in[6];
  float* outp = (float*)d_out;

  // workspace (~54.5 MB), lifetime aliasing:
  //   [0,8.39M)     part[8192][8][64] bf16 — aliases xbf[0,16M),
  //                 xbf dead before gemm2_8p writes part
  //   [34M,38M)     w2t
  //   [38M,38.25M)  w3t
  //   [38.5M,54.5M) h1
  char* ws = (char*)d_ws;
  unsigned short* xbf = (unsigned short*)ws;
  unsigned short* w1t = (unsigned short*)(ws + (size_t)16 * 1024 * 1024);
  unsigned short* part = (unsigned short*)ws;
  unsigned short* w2t = (unsigned short*)(ws + (size_t)34 * 1024 * 1024);
  unsigned short* w3t = (unsigned short*)(ws + (size_t)38 * 1024 * 1024);
  unsigned short* h1  = (unsigned short*)(ws + (size_t)38 * 1024 * 1024 + 512 * 1024);

  prepass<<<5632, 256, 0, stream>>>(x, W1, W2, W3, xbf, w1t, w2t, w3t);

  gemm1_8p<<<dim3(32, 8), 512, 0, stream>>>(xbf, w1t, b1, h1);
  gemm2_8p<<<dim3(32, 8), 512, 0, stream>>>(h1, w2t, b2, w3t, part);
  geom_reduce<<<512, 256, 0, stream>>>(part, b3, outp);
}